// Round 6
// baseline (31.992 us; speedup 1.0000x reference)
//
#include <hip/hip_runtime.h>
#include <math.h>

// Problem constants (match reference)
#define BB 32
#define TT 50
#define HH 76
#define WW 76
#define NA 5
#define NC 20
#define KK 25           // 5 + NC
#define HW (HH*WW)      // 5776
#define CPT 5           // cells per thread: all anchors of one spatial pos
#define TPB_CELLS HW    // 5776 threads per batch
#define MBX ((TPB_CELLS + 255)/256) // 23 main blocks per batch
#define GX (MBX + 1)    // +1 owner block per batch -> 24

#define RDLANE(v, t) __uint_as_float((unsigned)__builtin_amdgcn_readlane((int)__float_as_uint(v), (t)))

// R3/R5-proven clamped form: hit <=> acc > 0 <=> inter > 0.375*(pa+ba) <=> IoU > 0.6
// identical macro + iteration order in main & owner so the noobj subtraction cancels exactly
#define IOU_STEP(AX1, AX2, AY1, AY2, NPB, ACC) do {          \
    float iw_ = fminf(AX2, sx2) - fmaxf(AX1, sx1);           \
    float ih_ = fminf(AY2, sy2) - fmaxf(AY1, sy1);           \
    iw_ = fmaxf(iw_, 0.0f);  ih_ = fmaxf(ih_, 0.0f);         \
    float ns_ = (NPB) + sna;                                 \
    (ACC) = fmaxf((ACC), fmaf(iw_, ih_, ns_)); } while (0)

__global__ __launch_bounds__(256) void fused_kernel(
    const float* __restrict__ out, const float* __restrict__ tgt,
    const float* __restrict__ pri, float* __restrict__ result)
{
    const int b = blockIdx.y;
    const int tid = threadIdx.x;
    const int lane = tid & 63;
    const int tl = (lane < TT) ? lane : (TT - 1);

    // wave-held target table, built under FULL exec (uniform control flow):
    // lane t holds target t's box corners and -0.375*area
    const float* tp = tgt + ((size_t)b * TT + tl) * 5;
    float bx = tp[1], by = tp[2], bw = tp[3], bh = tp[4];
    float vx1 = fmaf(-0.5f, bw, bx);
    float vx2 = fmaf( 0.5f, bw, bx);
    float vy1 = fmaf(-0.5f, bh, by);
    float vy2 = fmaf( 0.5f, bh, by);
    float vna = -0.375f * (bw * bh);

    float mysum = 0.0f;

    if (blockIdx.x < MBX) {
        // ---- main path: 5 cells (all anchors of one spatial pos) per thread ----
        int k = blockIdx.x * 256 + tid;
        float valid = (k < TPB_CELLS) ? 1.0f : 0.0f;
        int rem = (k < TPB_CELLS) ? k : (TPB_CELLS - 1);
        int h = rem / WW;
        int w = rem - h * WW;

        const float* op0 = out + (size_t)b * KK * NA * HW + rem;
        float ax1[CPT], ax2[CPT], ay1[CPT], ay2[CPT], npb[CPT], o4v[CPT];
        #pragma unroll
        for (int n = 0; n < NA; ++n) {
            const float* op = op0 + (size_t)(n * KK) * HW;
            float o0 = op[0];
            float o1 = op[HW];
            float o2 = op[2*HW];
            float o3 = op[3*HW];
            o4v[n] = op[4*HW];
            float px = ((float)w + o0) * (1.0f/WW);
            float py = ((float)h + o1) * (1.0f/HH);
            float pw = pri[2*n]   * __expf(o2) * (1.0f/WW);
            float ph = pri[2*n+1] * __expf(o3) * (1.0f/HH);
            ax1[n] = fmaf(-0.5f, pw, px);  ax2[n] = fmaf(0.5f, pw, px);
            ay1[n] = fmaf(-0.5f, ph, py);  ay2[n] = fmaf(0.5f, ph, py);
            npb[n] = -0.375f * (pw * ph);
        }

        float acc[CPT];
        #pragma unroll
        for (int j = 0; j < CPT; ++j) acc[j] = -1.0f;

        #pragma unroll 10
        for (int t = 0; t < TT; ++t) {
            float sx1 = RDLANE(vx1, t);
            float sx2 = RDLANE(vx2, t);
            float sy1 = RDLANE(vy1, t);
            float sy2 = RDLANE(vy2, t);
            float sna = RDLANE(vna, t);
            IOU_STEP(ax1[0], ax2[0], ay1[0], ay2[0], npb[0], acc[0]);
            IOU_STEP(ax1[1], ax2[1], ay1[1], ay2[1], npb[1], acc[1]);
            IOU_STEP(ax1[2], ax2[2], ay1[2], ay2[2], npb[2], acc[2]);
            IOU_STEP(ax1[3], ax2[3], ay1[3], ay2[3], npb[3], acc[3]);
            IOU_STEP(ax1[4], ax2[4], ay1[4], ay2[4], npb[4], acc[4]);
        }

        float s = 0.0f;
        #pragma unroll
        for (int j = 0; j < CPT; ++j)
            s += (acc[j] > 0.0f) ? 0.0f : o4v[j] * o4v[j];
        mysum = s * valid;
    } else {
        // ---- owner path: FULLY UNIFORM across the block; liveness applied as
        // a multiply at the end. Lanes >= TT and waves 1..3 compute masked
        // duplicates of target TT-1 on valid addresses (all values finite). ----
        float cls = tp[0];
        int ci = (int)floorf(bx * WW);
        int cj = (int)floorf(by * HH);

        // anchor assignment: IoU of (0,0,bw,bh) vs (0,0,pw_cell,ph_cell), first-argmax
        const float* ob = out + (size_t)b * KK * NA * HW + (size_t)cj * WW + ci;
        float best = -1.0f; int bn = 0;
        #pragma unroll
        for (int n = 0; n < NA; ++n) {
            float e2 = ob[(size_t)(n*KK + 2) * HW];
            float e3 = ob[(size_t)(n*KK + 3) * HW];
            float pw = pri[2*n]   * __expf(e2) * (1.0f/WW);
            float ph = pri[2*n+1] * __expf(e3) * (1.0f/HH);
            float inter = fminf(bw, pw) * fminf(bh, ph);
            float iou = inter / (bw*bh + pw*ph - inter);
            if (iou > best) { best = iou; bn = n; }
        }
        int mycell = (cj*WW + ci)*NA + bn;   // produced under full exec

        // duplicate-target resolution: later t wins for the same cell.
        // Only lanes 0..TT-1 are read; their mycell is the real per-target value.
        bool dead = false;
        #pragma unroll 10
        for (int t2 = 0; t2 < TT; ++t2) {
            int c2 = __builtin_amdgcn_readlane(mycell, t2);
            dead = dead || (c2 == mycell && t2 > tid);
        }
        float live = (tid < TT && !dead) ? 1.0f : 0.0f;

        int rem = cj*WW + ci;
        const float* op = out + ((size_t)(b*NA + bn) * KK) * HW + rem;
        float o0 = op[0];
        float o1 = op[HW];
        float o2 = op[2*HW];
        float o3 = op[3*HW];
        float o4 = op[4*HW];

        float tx = bx * WW - (float)ci;
        float ty = by * HH - (float)cj;
        float tw = __logf(bw * WW / pri[2*bn]);
        float th = __logf(bh * HH / pri[2*bn+1]);
        if (tw != tw) tw = 0.0f;  // NaN guard (matches reference)
        if (th != th) th = 0.0f;
        float sc = 2.0f - bw * bh;

        float d0 = sc * (tx - o0);
        float d1 = sc * (ty - o1);
        float d2 = sc * (tw - o2);
        float d3 = sc * (th - o3);
        float dob = 5.0f * (1.0f - o4);
        float s = d0*d0 + d1*d1 + d2*d2 + d3*d3 + dob*dob;
        int tc = (int)floorf(cls);
        #pragma unroll
        for (int c = 0; c < NC; ++c) {
            float oc = op[(size_t)(5 + c) * HW];
            float d = ((c == tc) ? 1.0f : 0.0f) - oc;
            s += d * d;
        }

        // recompute this cell's iou-hit with the bitwise-identical chain,
        // subtract the noobj term the main path added for this cell
        float px = ((float)ci + o0) * (1.0f/WW);
        float py = ((float)cj + o1) * (1.0f/HH);
        float pw = pri[2*bn]   * __expf(o2) * (1.0f/WW);
        float ph = pri[2*bn+1] * __expf(o3) * (1.0f/HH);
        float Ax1 = fmaf(-0.5f, pw, px), Ax2 = fmaf(0.5f, pw, px);
        float Ay1 = fmaf(-0.5f, ph, py), Ay2 = fmaf(0.5f, ph, py);
        float Npb = -0.375f * (pw * ph);
        float acc = -1.0f;
        #pragma unroll 10
        for (int t2 = 0; t2 < TT; ++t2) {
            float sx1 = RDLANE(vx1, t2);
            float sx2 = RDLANE(vx2, t2);
            float sy1 = RDLANE(vy1, t2);
            float sy2 = RDLANE(vy2, t2);
            float sna = RDLANE(vna, t2);
            IOU_STEP(Ax1, Ax2, Ay1, Ay2, Npb, acc);
        }
        s -= (acc > 0.0f) ? 0.0f : o4 * o4;
        mysum = s * live;
    }

    // deterministic block reduction: wave shuffle + LDS across 4 waves,
    // then one device-scope atomicAdd per block into the scalar output.
    #pragma unroll
    for (int off = 32; off > 0; off >>= 1)
        mysum += __shfl_down(mysum, off, 64);
    __shared__ float swave[4];
    if ((tid & 63) == 0) swave[tid >> 6] = mysum;
    __syncthreads();
    if (tid == 0)
        atomicAdd(result, swave[0] + swave[1] + swave[2] + swave[3]);
}

extern "C" void kernel_launch(void* const* d_in, const int* in_sizes, int n_in,
                              void* d_out, int out_size, void* d_ws, size_t ws_size,
                              hipStream_t stream) {
    const float* output = (const float*)d_in[0];
    const float* target = (const float*)d_in[1];
    const float* priors = (const float*)d_in[2];
    float* result = (float*)d_out;

    // zero the scalar accumulator each call (captured as a graph memset node;
    // required because the harness does not re-poison between replays)
    hipMemsetAsync(result, 0, sizeof(float), stream);
    fused_kernel<<<dim3(GX, BB), 256, 0, stream>>>(output, target, priors, result);
}